// Round 3
// baseline (24185.803 us; speedup 1.0000x reference)
//
#include <hip/hip_runtime.h>
#include <hip/hip_cooperative_groups.h>
#include <math.h>

// LSTM_360 R3: single persistent cooperative kernel, weights in VGPRs.
// Grid 256 blocks x 256 thr (1 block/CU). Per step (one grid.sync each):
//  Stage A (all blocks): gates GEMM tile M=64,N=32 (K=1280) + cell update.
//    Each wave holds its 16-col Wc slice in 160 persistent VGPRs (loaded once).
//  Stage B (blocks 0..31): logits_{t-1} = h_{t-1} @ Wout^T + bout.
//  Stage C (blocks 32..63): log_softmax of logits_{t-2} -> out.

namespace cg = cooperative_groups;

#define TT  512
#define BB  128
#define NIN 256
#define NH  1024
#define G4  4096
#define KK  1280

typedef __bf16 bf16_t;
typedef bf16_t bf16x8 __attribute__((ext_vector_type(8)));
typedef float  f32x4  __attribute__((ext_vector_type(4)));

#define MFMA(a, b, c) __builtin_amdgcn_mfma_f32_16x16x32_bf16((a), (b), (c), 0, 0, 0)

// ---------------- prep kernels ----------------

// Wc[n][k]: n = j*4+g ; k<256 -> Wxh[g*1024+j][k], else Whh[g*1024+j][k-256]
__global__ void conv_w_kernel(const float* __restrict__ Wxh,
                              const float* __restrict__ Whh,
                              bf16_t* __restrict__ Wc) {
  const int n = blockIdx.y;
  const int k = blockIdx.x * 256 + threadIdx.x;
  const int g = n & 3, j = n >> 2;
  float v = (k < NIN) ? Wxh[(size_t)(g * NH + j) * NIN + k]
                      : Whh[(size_t)(g * NH + j) * NH + (k - NIN)];
  Wc[(size_t)n * KK + k] = (bf16_t)v;
}

__global__ void conv_f2b_kernel(const float* __restrict__ src,
                                bf16_t* __restrict__ dst, int n4) {
  int i = blockIdx.x * 256 + threadIdx.x;
  if (i < n4) {
    float4 v = ((const float4*)src)[i];
    dst[i * 4 + 0] = (bf16_t)v.x;
    dst[i * 4 + 1] = (bf16_t)v.y;
    dst[i * 4 + 2] = (bf16_t)v.z;
    dst[i * 4 + 3] = (bf16_t)v.w;
  }
}

__global__ void prep_bias_kernel(const float* __restrict__ bxh,
                                 const float* __restrict__ bhh,
                                 float* __restrict__ bsum4) {
  int n = blockIdx.x * 256 + threadIdx.x;  // 0..4095
  int g = n & 3, j = n >> 2;
  bsum4[n] = bxh[g * NH + j] + bhh[g * NH + j];
}

// ---------------- persistent kernel ----------------

__global__ __launch_bounds__(256, 1) void lstm_persistent(
    const bf16_t* __restrict__ x_bf,   // [TT][BB][NIN]
    const bf16_t* __restrict__ Wc,     // [G4][KK] gate-interleaved rows
    const float*  __restrict__ bsum4,  // [G4] gate-interleaved
    bf16_t* __restrict__ hb0,          // [BB][NH]
    bf16_t* __restrict__ hb1,          // [BB][NH]
    float*  __restrict__ lgA,          // [BB][NIN]
    float*  __restrict__ lgB,          // [BB][NIN]
    const bf16_t* __restrict__ WoutB,  // [NIN][NH]
    const float*  __restrict__ bout,   // [NIN]
    float*  __restrict__ out)          // [TT][BB][NIN]
{
  cg::grid_group grid = cg::this_grid();
  __shared__ float gs[64 * 40];        // gate preacts, stride 40 (16B-aligned rows)
  __shared__ float red[2][4][4];

  const int blk  = blockIdx.x;
  const int tid  = threadIdx.x;
  const int lane = tid & 63;
  const int wv   = tid >> 6;
  const int l16  = lane & 15;
  const int lq   = lane >> 4;

  // stage A geometry: block tile M=64 x N=32; wave tile 32m x 16n
  const int mb = (blk & 1) * 64;
  const int ns = blk >> 1;             // n-slice 0..127 (8 hidden units each)
  const int wm = wv & 1, wn = wv >> 1;
  const int m0 = mb + wm * 32;
  const int n0 = ns * 32 + wn * 16;

  // persistent weight fragments: 40 x bf16x8 = 160 VGPRs (loaded once)
  bf16x8 w[40];
  {
    const bf16_t* wp = Wc + (size_t)(n0 + l16) * KK + lq * 8;
#pragma unroll
    for (int kk = 0; kk < 40; ++kk) w[kk] = *(const bf16x8*)(wp + kk * 32);
  }

  // per-thread cell state: pairs (b_l, jl) and (b_l+32, jl)
  const int b_l = tid >> 3;            // 0..31
  const int jl  = tid & 7;
  const int jg  = ns * 8 + jl;         // global hidden index
  const float4 bs = ((const float4*)bsum4)[jg];
  float c0 = 0.f, c1 = 0.f;

  // stage B geometry (blocks 0..31): wave gw handles 16x16 tile of [128][256]
  const int gw  = blk * 4 + wv;
  const int bm0 = (gw >> 4) * 16;
  const int bn0 = (gw & 15) * 16;
  float boutv = 0.f;
  const bf16_t* wob = WoutB;
  if (blk < 32) {
    boutv = bout[bn0 + l16];
    wob = WoutB + (size_t)(bn0 + l16) * NH + lq * 8;
  }

  bf16_t* hb[2] = {hb0, hb1};
  float*  lg[2] = {lgA, lgB};

  for (int t = 0; t < TT + 2; ++t) {
    const bf16_t* hc = hb[t & 1];
    bf16_t*       hn = hb[(t + 1) & 1];

    if (t < TT) {
      // ---- Stage A: gates GEMM + cell update ----
      f32x4 a00 = {0,0,0,0}, a01 = {0,0,0,0}, a10 = {0,0,0,0}, a11 = {0,0,0,0};
      const bf16_t* ax = x_bf + (size_t)t * BB * NIN + (size_t)(m0 + l16) * NIN + lq * 8;
#pragma unroll
      for (int kk = 0; kk < 8; ++kk) {
        bf16x8 r0 = *(const bf16x8*)(ax + kk * 32);
        bf16x8 r1 = *(const bf16x8*)(ax + 16 * NIN + kk * 32);
        a00 = MFMA(r0, w[kk], a00);
        a10 = MFMA(r1, w[kk], a10);
      }
      const bf16_t* ah = hc + (size_t)(m0 + l16) * NH + lq * 8;
#pragma unroll
      for (int kk = 0; kk < 16; ++kk) {
        bf16x8 r0 = *(const bf16x8*)(ah + kk * 32);
        bf16x8 r1 = *(const bf16x8*)(ah + 16 * NH + kk * 32);
        a00 = MFMA(r0, w[8 + kk], a00);
        a10 = MFMA(r1, w[8 + kk], a10);
      }
#pragma unroll
      for (int kk = 16; kk < 32; ++kk) {
        bf16x8 r0 = *(const bf16x8*)(ah + kk * 32);
        bf16x8 r1 = *(const bf16x8*)(ah + 16 * NH + kk * 32);
        a01 = MFMA(r0, w[8 + kk], a01);
        a11 = MFMA(r1, w[8 + kk], a11);
      }
      f32x4 acc0 = a00 + a01;
      f32x4 acc1 = a10 + a11;

      // D layout: col = lane&15, row = lq*4 + r
#pragma unroll
      for (int r = 0; r < 4; ++r) {
        gs[(wm * 32 + lq * 4 + r) * 40 + wn * 16 + l16]      = acc0[r];
        gs[(wm * 32 + 16 + lq * 4 + r) * 40 + wn * 16 + l16] = acc1[r];
      }
      __syncthreads();

      // cell update (2 (b,j) pairs per thread; c lives in registers)
      {
        float4 g0 = *(const float4*)&gs[b_l * 40 + jl * 4];
        float4 g1 = *(const float4*)&gs[(b_l + 32) * 40 + jl * 4];
        float gi = g0.x + bs.x, gf = g0.y + bs.y, gg = g0.z + bs.z, go = g0.w + bs.w;
        float si = 1.f / (1.f + __expf(-gi));
        float sf = 1.f / (1.f + __expf(-gf));
        float so = 1.f / (1.f + __expf(-go));
        c0 = sf * c0 + si * tanhf(gg);
        hn[(size_t)(mb + b_l) * NH + jg] = (bf16_t)(so * tanhf(c0));

        gi = g1.x + bs.x; gf = g1.y + bs.y; gg = g1.z + bs.z; go = g1.w + bs.w;
        si = 1.f / (1.f + __expf(-gi));
        sf = 1.f / (1.f + __expf(-gf));
        so = 1.f / (1.f + __expf(-go));
        c1 = sf * c1 + si * tanhf(gg);
        hn[(size_t)(mb + b_l + 32) * NH + jg] = (bf16_t)(so * tanhf(c1));
      }
    }

    if (blk < 32 && t >= 1 && t <= TT) {
      // ---- Stage B: logits for step t-1 (reads h_{t-1} = hc) ----
      const bf16_t* ap = hc + (size_t)(bm0 + l16) * NH + lq * 8;
      f32x4 acc = {0,0,0,0};
#pragma unroll
      for (int kk = 0; kk < 32; ++kk) {
        bf16x8 a = *(const bf16x8*)(ap + kk * 32);
        bf16x8 b = *(const bf16x8*)(wob + kk * 32);
        acc = MFMA(a, b, acc);
      }
      float* lw = lg[t & 1];
#pragma unroll
      for (int r = 0; r < 4; ++r)
        lw[(size_t)(bm0 + lq * 4 + r) * NIN + bn0 + l16] = acc[r] + boutv;
    }

    if (blk >= 32 && blk < 64 && t >= 2) {
      // ---- Stage C: log_softmax of logits_{t-2} ----
      const float* lr = lg[(t + 1) & 1];
      const int b0 = (blk - 32) * 4;
      float v[4], mx[4], sm[4];
#pragma unroll
      for (int r = 0; r < 4; ++r) v[r] = lr[(size_t)(b0 + r) * NIN + tid];
#pragma unroll
      for (int r = 0; r < 4; ++r) mx[r] = v[r];
#pragma unroll
      for (int off = 32; off > 0; off >>= 1)
#pragma unroll
        for (int r = 0; r < 4; ++r) mx[r] = fmaxf(mx[r], __shfl_xor(mx[r], off));
      if (lane == 0)
#pragma unroll
        for (int r = 0; r < 4; ++r) red[0][wv][r] = mx[r];
      __syncthreads();
#pragma unroll
      for (int r = 0; r < 4; ++r)
        mx[r] = fmaxf(fmaxf(red[0][0][r], red[0][1][r]),
                      fmaxf(red[0][2][r], red[0][3][r]));
#pragma unroll
      for (int r = 0; r < 4; ++r) sm[r] = __expf(v[r] - mx[r]);
#pragma unroll
      for (int off = 32; off > 0; off >>= 1)
#pragma unroll
        for (int r = 0; r < 4; ++r) sm[r] += __shfl_xor(sm[r], off);
      if (lane == 0)
#pragma unroll
        for (int r = 0; r < 4; ++r) red[1][wv][r] = sm[r];
      __syncthreads();
      float* ot = out + (size_t)(t - 2) * BB * NIN + (size_t)b0 * NIN;
#pragma unroll
      for (int r = 0; r < 4; ++r) {
        float S = red[1][0][r] + red[1][1][r] + red[1][2][r] + red[1][3][r];
        ot[(size_t)r * NIN + tid] = v[r] - mx[r] - logf(S);
      }
      __syncthreads();  // protect red[] before next iteration's reuse
    }

    grid.sync();
  }
}

// ---------------- launcher ----------------

extern "C" void kernel_launch(void* const* d_in, const int* in_sizes, int n_in,
                              void* d_out, int out_size, void* d_ws, size_t ws_size,
                              hipStream_t stream) {
  const float* inp  = (const float*)d_in[0];
  const float* Wxh  = (const float*)d_in[1];
  const float* bxh  = (const float*)d_in[2];
  const float* Whh  = (const float*)d_in[3];
  const float* bhh  = (const float*)d_in[4];
  const float* Wout = (const float*)d_in[5];
  const float* bout = (const float*)d_in[6];
  float* outp = (float*)d_out;

  // workspace carve (~45.3 MB)
  char* p = (char*)d_ws;
  bf16_t* Wc    = (bf16_t*)p; p += (size_t)G4 * KK * 2;        // 10.49 MB
  bf16_t* x_bf  = (bf16_t*)p; p += (size_t)TT * BB * NIN * 2;  // 33.55 MB
  bf16_t* WoutB = (bf16_t*)p; p += (size_t)NIN * NH * 2;       // 0.52 MB
  bf16_t* h0    = (bf16_t*)p; p += (size_t)BB * NH * 2;
  bf16_t* h1    = (bf16_t*)p; p += (size_t)BB * NH * 2;
  float*  bsum4 = (float*)p;  p += (size_t)G4 * 4;
  float*  lg0   = (float*)p;  p += (size_t)BB * NIN * 4;
  float*  lg1   = (float*)p;  p += (size_t)BB * NIN * 4;

  conv_w_kernel<<<dim3(KK / 256, G4), 256, 0, stream>>>(Wxh, Whh, Wc);
  conv_f2b_kernel<<<(TT * BB * NIN / 4 + 255) / 256, 256, 0, stream>>>(
      inp, x_bf, TT * BB * NIN / 4);
  conv_f2b_kernel<<<(NIN * NH / 4 + 255) / 256, 256, 0, stream>>>(
      Wout, WoutB, NIN * NH / 4);
  prep_bias_kernel<<<G4 / 256, 256, 0, stream>>>(bxh, bhh, bsum4);
  hipMemsetAsync(h0, 0, (size_t)BB * NH * 2, stream);

  void* args[] = {&x_bf, &Wc, &bsum4, &h0, &h1, &lg0, &lg1, &WoutB, &bout, &outp};
  hipLaunchCooperativeKernel((void*)lstm_persistent, dim3(256), dim3(256),
                             args, 0, stream);
}

// Round 4
// 11150.198 us; speedup vs baseline: 2.1691x; 2.1691x over previous
//
#include <hip/hip_runtime.h>
#include <math.h>

// LSTM_360 R4: dispatch-per-step (grid.sync proved ~40us/step — abandoned).
// Per step, ONE 192-block dispatch:
//  blocks   0..127: Stage A — gates GEMM (M=128,N=4096,K=1280), block tile 64x64,
//                   wave tile 32x32 (4 acc), + fused cell update -> h_t (bf16)
//  blocks 128..159: Stage B — logits_{t-1} = h_{t-1} @ Wout^T + bout (MFMA)
//  blocks 160..191: Stage C — log_softmax(logits_{t-2}) -> out
// Weight layout Wc[n][k], n = j*4+gate, so a block's 64-col slice = 16 hidden units.

#define TT  512
#define BB  128
#define NIN 256
#define NH  1024
#define G4  4096
#define KK  1280

typedef __bf16 bf16_t;
typedef bf16_t bf16x8 __attribute__((ext_vector_type(8)));
typedef float  f32x4  __attribute__((ext_vector_type(4)));

#define MFMA(a, b, c) __builtin_amdgcn_mfma_f32_16x16x32_bf16((a), (b), (c), 0, 0, 0)

// ---------------- prep kernels ----------------

__global__ void conv_w_kernel(const float* __restrict__ Wxh,
                              const float* __restrict__ Whh,
                              bf16_t* __restrict__ Wc) {
  const int n = blockIdx.y;
  const int k = blockIdx.x * 256 + threadIdx.x;
  const int g = n & 3, j = n >> 2;
  float v = (k < NIN) ? Wxh[(size_t)(g * NH + j) * NIN + k]
                      : Whh[(size_t)(g * NH + j) * NH + (k - NIN)];
  Wc[(size_t)n * KK + k] = (bf16_t)v;
}

__global__ void conv_f2b_kernel(const float* __restrict__ src,
                                bf16_t* __restrict__ dst, int n4) {
  int i = blockIdx.x * 256 + threadIdx.x;
  if (i < n4) {
    float4 v = ((const float4*)src)[i];
    dst[i * 4 + 0] = (bf16_t)v.x;
    dst[i * 4 + 1] = (bf16_t)v.y;
    dst[i * 4 + 2] = (bf16_t)v.z;
    dst[i * 4 + 3] = (bf16_t)v.w;
  }
}

__global__ void prep_bias_kernel(const float* __restrict__ bxh,
                                 const float* __restrict__ bhh,
                                 float* __restrict__ bsum4) {
  int n = blockIdx.x * 256 + threadIdx.x;  // 0..4095
  int g = n & 3, j = n >> 2;
  bsum4[n] = bxh[g * NH + j] + bhh[g * NH + j];
}

// ---------------- fused per-step kernel ----------------

__global__ __launch_bounds__(256) void fused_step(
    int t,
    const bf16_t* __restrict__ x_bf,    // [TT][BB][NIN]
    const bf16_t* __restrict__ Wc,      // [G4][KK] gate-interleaved rows
    const float*  __restrict__ bsum4,   // [G4] gate-interleaved
    const bf16_t* __restrict__ h_cur,   // [BB][NH] = h_{t-1}
    bf16_t*       __restrict__ h_next,  // [BB][NH] = h_t
    float*        __restrict__ c,       // [BB][NH]
    const bf16_t* __restrict__ WoutB,   // [NIN][NH]
    const float*  __restrict__ bout,    // [NIN]
    float*        __restrict__ logits_w,// [BB][NIN] write (step t-1)
    const float*  __restrict__ logits_r,// [BB][NIN] read  (step t-2)
    float*        __restrict__ out)     // [TT][BB][NIN]
{
  const int blk  = blockIdx.x;
  const int tid  = threadIdx.x;
  const int lane = tid & 63;
  const int wv   = tid >> 6;
  const int l16  = lane & 15;
  const int lq   = lane >> 4;

  if (blk < 128) {
    // ---- Stage A ----
    if (t >= TT) return;
    __shared__ float gs[64 * 68];      // [row=batch][col=gate], pad 68

    const int mb    = (blk & 1) * 64;
    const int ns    = blk >> 1;        // 0..63 -> 16 hidden units each
    const int nbase = ns * 64;
    const int wm = wv & 1, wn = wv >> 1;
    const int m0 = mb + wm * 32;
    const int n0 = nbase + wn * 32;

    const bf16_t* ax  = x_bf + (size_t)t * BB * NIN + (size_t)(m0 + l16) * NIN + lq * 8;
    const bf16_t* ah  = h_cur + (size_t)(m0 + l16) * NH + lq * 8;
    const bf16_t* b0p = Wc + (size_t)(n0 + l16) * KK + lq * 8;
    const bf16_t* b1p = Wc + (size_t)(n0 + 16 + l16) * KK + lq * 8;

    f32x4 a00 = {0,0,0,0}, a01 = {0,0,0,0}, a10 = {0,0,0,0}, a11 = {0,0,0,0};

#pragma unroll
    for (int kk = 0; kk < 8; ++kk) {
      bf16x8 r0 = *(const bf16x8*)(ax + kk * 32);
      bf16x8 r1 = *(const bf16x8*)(ax + 16 * NIN + kk * 32);
      bf16x8 b0 = *(const bf16x8*)(b0p + kk * 32);
      bf16x8 b1 = *(const bf16x8*)(b1p + kk * 32);
      a00 = MFMA(r0, b0, a00); a01 = MFMA(r0, b1, a01);
      a10 = MFMA(r1, b0, a10); a11 = MFMA(r1, b1, a11);
    }
#pragma unroll 8
    for (int kk = 0; kk < 32; ++kk) {
      bf16x8 r0 = *(const bf16x8*)(ah + kk * 32);
      bf16x8 r1 = *(const bf16x8*)(ah + 16 * NH + kk * 32);
      bf16x8 b0 = *(const bf16x8*)(b0p + NIN + kk * 32);
      bf16x8 b1 = *(const bf16x8*)(b1p + NIN + kk * 32);
      a00 = MFMA(r0, b0, a00); a01 = MFMA(r0, b1, a01);
      a10 = MFMA(r1, b0, a10); a11 = MFMA(r1, b1, a11);
    }

    // D layout: col = lane&15, row = lq*4 + r
#pragma unroll
    for (int r = 0; r < 4; ++r) {
      const int rr0 = wm * 32 + lq * 4 + r;
      gs[rr0 * 68 + wn * 32 + l16]             = a00[r];
      gs[rr0 * 68 + wn * 32 + 16 + l16]        = a01[r];
      gs[(rr0 + 16) * 68 + wn * 32 + l16]      = a10[r];
      gs[(rr0 + 16) * 68 + wn * 32 + 16 + l16] = a11[r];
    }
    __syncthreads();

    // cell update: thread -> batch row b_l = tid>>2, 4 hidden units
    const int b_l = tid >> 2;
#pragma unroll
    for (int p = 0; p < 4; ++p) {
      const int jl = (tid & 3) + p * 4;         // 0..15
      const int j  = ns * 16 + jl;              // global hidden idx
      float4 g4 = *(const float4*)&gs[b_l * 68 + jl * 4];
      float4 bs = ((const float4*)bsum4)[j];
      const float gi = g4.x + bs.x;
      const float gf = g4.y + bs.y;
      const float gg = g4.z + bs.z;
      const float go = g4.w + bs.w;
      const float si = 1.f / (1.f + __expf(-gi));
      const float sf = 1.f / (1.f + __expf(-gf));
      const float so = 1.f / (1.f + __expf(-go));
      const size_t idx = (size_t)(mb + b_l) * NH + j;
      const float cn = sf * c[idx] + si * tanhf(gg);
      c[idx] = cn;
      h_next[idx] = (bf16_t)(so * tanhf(cn));
    }
  } else if (blk < 160) {
    // ---- Stage B: logits for step t-1 ----
    if (t < 1 || t > TT) return;
    const int gw  = (blk - 128) * 4 + wv;       // 0..127
    const int bm0 = (gw >> 4) * 16;
    const int bn0 = (gw & 15) * 16;

    const bf16_t* ap = h_cur + (size_t)(bm0 + l16) * NH + lq * 8;
    const bf16_t* bp = WoutB + (size_t)(bn0 + l16) * NH + lq * 8;
    f32x4 acc = {0,0,0,0};
#pragma unroll 8
    for (int kk = 0; kk < 32; ++kk) {
      bf16x8 a = *(const bf16x8*)(ap + kk * 32);
      bf16x8 b = *(const bf16x8*)(bp + kk * 32);
      acc = MFMA(a, b, acc);
    }
    const float bo = bout[bn0 + l16];
#pragma unroll
    for (int r = 0; r < 4; ++r)
      logits_w[(size_t)(bm0 + lq * 4 + r) * NIN + bn0 + l16] = acc[r] + bo;
  } else {
    // ---- Stage C: log_softmax of logits_{t-2} ----
    if (t < 2) return;
    __shared__ float red[2][4][4];
    const int b0 = (blk - 160) * 4;
    float v[4], mx[4], sm[4];
#pragma unroll
    for (int r = 0; r < 4; ++r) v[r] = logits_r[(size_t)(b0 + r) * NIN + tid];
#pragma unroll
    for (int r = 0; r < 4; ++r) mx[r] = v[r];
#pragma unroll
    for (int off = 32; off > 0; off >>= 1)
#pragma unroll
      for (int r = 0; r < 4; ++r) mx[r] = fmaxf(mx[r], __shfl_xor(mx[r], off));
    if (lane == 0)
#pragma unroll
      for (int r = 0; r < 4; ++r) red[0][wv][r] = mx[r];
    __syncthreads();
#pragma unroll
    for (int r = 0; r < 4; ++r)
      mx[r] = fmaxf(fmaxf(red[0][0][r], red[0][1][r]),
                    fmaxf(red[0][2][r], red[0][3][r]));
#pragma unroll
    for (int r = 0; r < 4; ++r) sm[r] = __expf(v[r] - mx[r]);
#pragma unroll
    for (int off = 32; off > 0; off >>= 1)
#pragma unroll
      for (int r = 0; r < 4; ++r) sm[r] += __shfl_xor(sm[r], off);
    if (lane == 0)
#pragma unroll
      for (int r = 0; r < 4; ++r) red[1][wv][r] = sm[r];
    __syncthreads();
    float* ot = out + (size_t)(t - 2) * BB * NIN + (size_t)b0 * NIN;
#pragma unroll
    for (int r = 0; r < 4; ++r) {
      float S = red[1][0][r] + red[1][1][r] + red[1][2][r] + red[1][3][r];
      ot[(size_t)r * NIN + tid] = v[r] - mx[r] - logf(S);
    }
  }
}

// ---------------- launcher ----------------

extern "C" void kernel_launch(void* const* d_in, const int* in_sizes, int n_in,
                              void* d_out, int out_size, void* d_ws, size_t ws_size,
                              hipStream_t stream) {
  const float* inp  = (const float*)d_in[0];
  const float* Wxh  = (const float*)d_in[1];
  const float* bxh  = (const float*)d_in[2];
  const float* Whh  = (const float*)d_in[3];
  const float* bhh  = (const float*)d_in[4];
  const float* Wout = (const float*)d_in[5];
  const float* bout = (const float*)d_in[6];
  float* out = (float*)d_out;

  // workspace carve (~46 MB)
  char* p = (char*)d_ws;
  bf16_t* Wc    = (bf16_t*)p; p += (size_t)G4 * KK * 2;        // 10.49 MB
  bf16_t* x_bf  = (bf16_t*)p; p += (size_t)TT * BB * NIN * 2;  // 33.55 MB
  bf16_t* WoutB = (bf16_t*)p; p += (size_t)NIN * NH * 2;       // 0.52 MB
  bf16_t* h0    = (bf16_t*)p; p += (size_t)BB * NH * 2;
  bf16_t* h1    = (bf16_t*)p; p += (size_t)BB * NH * 2;
  float*  cbuf  = (float*)p;  p += (size_t)BB * NH * 4;
  float*  bsum4 = (float*)p;  p += (size_t)G4 * 4;
  float*  lg0   = (float*)p;  p += (size_t)BB * NIN * 4;
  float*  lg1   = (float*)p;  p += (size_t)BB * NIN * 4;

  conv_w_kernel<<<dim3(KK / 256, G4), 256, 0, stream>>>(Wxh, Whh, Wc);
  conv_f2b_kernel<<<(TT * BB * NIN / 4 + 255) / 256, 256, 0, stream>>>(
      inp, x_bf, TT * BB * NIN / 4);
  conv_f2b_kernel<<<(NIN * NH / 4 + 255) / 256, 256, 0, stream>>>(
      Wout, WoutB, NIN * NH / 4);
  prep_bias_kernel<<<G4 / 256, 256, 0, stream>>>(bxh, bhh, bsum4);
  hipMemsetAsync(h0, 0, (size_t)BB * NH * 2, stream);
  hipMemsetAsync(cbuf, 0, (size_t)BB * NH * 4, stream);

  bf16_t* hb[2] = {h0, h1};
  float*  lg[2] = {lg0, lg1};
  for (int t = 0; t < TT + 2; ++t) {
    fused_step<<<192, 256, 0, stream>>>(
        t, x_bf, Wc, bsum4,
        hb[t & 1], hb[(t + 1) & 1], cbuf,
        WoutB, bout,
        lg[t & 1],        // write: logits for step t-1
        lg[(t + 1) & 1],  // read:  logits for step t-2
        out);
  }
}